// Round 5
// baseline (1280.124 us; speedup 1.0000x reference)
//
#include <hip/hip_runtime.h>
#include <hip/hip_bf16.h>

typedef __bf16 bf16_t;
typedef __attribute__((ext_vector_type(8))) __bf16 bf16x8;
typedef __attribute__((ext_vector_type(4))) __bf16 bf16x4;
typedef __attribute__((ext_vector_type(4))) float f32x4;

#define GM 16384
#define GN 4096
#define GK 4096

// async global->LDS, 16B per lane; LDS dest is wave-uniform base + lane*16
#define GLOAD16(gp, lp)                                                        \
  __builtin_amdgcn_global_load_lds(                                            \
      (const __attribute__((address_space(1))) unsigned int*)(gp),             \
      (__attribute__((address_space(3))) unsigned int*)(lp), 16, 0, 0)

// ---------------------------------------------------------------------------
// Kernel 1: convert x (fp32) -> bf16, 16 elements (64B) per thread for ILP
// ---------------------------------------------------------------------------
__global__ __launch_bounds__(256) void cvt_x_kernel(
    const float* __restrict__ in, bf16_t* __restrict__ outb) {
  long i = (long)blockIdx.x * blockDim.x + threadIdx.x;
  const f32x4* v = (const f32x4*)in;
  f32x4 a = v[4 * i + 0];
  f32x4 b = v[4 * i + 1];
  f32x4 c = v[4 * i + 2];
  f32x4 d = v[4 * i + 3];
  bf16x8 r0, r1;
  r0[0] = (__bf16)a[0]; r0[1] = (__bf16)a[1]; r0[2] = (__bf16)a[2]; r0[3] = (__bf16)a[3];
  r0[4] = (__bf16)b[0]; r0[5] = (__bf16)b[1]; r0[6] = (__bf16)b[2]; r0[7] = (__bf16)b[3];
  r1[0] = (__bf16)c[0]; r1[1] = (__bf16)c[1]; r1[2] = (__bf16)c[2]; r1[3] = (__bf16)c[3];
  r1[4] = (__bf16)d[0]; r1[5] = (__bf16)d[1]; r1[6] = (__bf16)d[2]; r1[7] = (__bf16)d[3];
  ((bf16x8*)outb)[2 * i + 0] = r0;
  ((bf16x8*)outb)[2 * i + 1] = r1;
}

// ---------------------------------------------------------------------------
// Kernel 2: bpt[er][o] = probs[e] * B[e][o][r]
// thread t owns one o: reads 16 contiguous floats (coalesced 64B chunks),
// writes 16 coalesced stores (one per r, lanes -> consecutive o).
// ---------------------------------------------------------------------------
__global__ __launch_bounds__(256) void make_bpt_kernel(
    const float* __restrict__ Bw, const float* __restrict__ probs,
    float* __restrict__ bpt) {
  int e = blockIdx.x >> 4;
  int o = ((blockIdx.x & 15) << 8) + threadIdx.x;
  float p = probs[e];
  const f32x4* src = (const f32x4*)(Bw + ((size_t)e << 16) + (size_t)o * 16);
  f32x4 v0 = src[0], v1 = src[1], v2 = src[2], v3 = src[3];
  float* dst = bpt + ((size_t)e * 16) * 4096 + o;
#pragma unroll
  for (int r = 0; r < 4; ++r) dst[r * 4096] = p * v0[r];
#pragma unroll
  for (int r = 0; r < 4; ++r) dst[(r + 4) * 4096] = p * v1[r];
#pragma unroll
  for (int r = 0; r < 4; ++r) dst[(r + 8) * 4096] = p * v2[r];
#pragma unroll
  for (int r = 0; r < 4; ++r) dst[(r + 12) * 4096] = p * v3[r];
}

// ---------------------------------------------------------------------------
// Kernel 3: weff[o][d] = bf16( W[o][d] + sum_er bpt[er][o] * A[er][d] )
// (round-2 version, measured 82us)
// ---------------------------------------------------------------------------
__global__ __launch_bounds__(256) void weff_kernel(
    const float* __restrict__ W, const float* __restrict__ Aw,
    const float* __restrict__ bpt, bf16_t* __restrict__ weffp) {
  __shared__ __align__(16) float At[64 * 64];  // [er][d] 16KB
  __shared__ __align__(16) float Bt[64 * 64];  // [er][o] 16KB
  int tid = threadIdx.x;
  int d0 = (blockIdx.x & 63) << 6;
  int o0 = (blockIdx.x >> 6) << 6;
  int tx = tid & 15, ty = tid >> 4;

  float acc[4][4] = {};

  for (int kc = 0; kc < 256; kc += 64) {
    __syncthreads();
#pragma unroll
    for (int q = 0; q < 4; ++q) {
      int er_l = (tid >> 4) + q * 16;
      f32x4 va = *(const f32x4*)&Aw[(long)(kc + er_l) * 4096 + d0 + tx * 4];
      *(f32x4*)&At[er_l * 64 + tx * 4] = va;
      f32x4 vb = *(const f32x4*)&bpt[(long)(kc + er_l) * 4096 + o0 + tx * 4];
      *(f32x4*)&Bt[er_l * 64 + tx * 4] = vb;
    }
    __syncthreads();
#pragma unroll 8
    for (int kk = 0; kk < 64; ++kk) {
      f32x4 av = *(const f32x4*)&At[kk * 64 + tx * 4];
      f32x4 bv = *(const f32x4*)&Bt[kk * 64 + ty * 4];
#pragma unroll
      for (int i = 0; i < 4; ++i)
#pragma unroll
        for (int j = 0; j < 4; ++j) acc[i][j] = fmaf(bv[i], av[j], acc[i][j]);
    }
  }

#pragma unroll
  for (int i = 0; i < 4; ++i) {
    int o = o0 + ty * 4 + i;
    f32x4 w = *(const f32x4*)&W[(long)o * 4096 + d0 + tx * 4];
    bf16x4 ov;
#pragma unroll
    for (int j = 0; j < 4; ++j) ov[j] = (__bf16)(w[j] + acc[i][j]);
    *(bf16x4*)&weffp[(long)o * 4096 + d0 + tx * 4] = ov;
  }
}

// ---------------------------------------------------------------------------
// Kernel 4: out[m][n] = sum_k xb[m][k]*weff[n][k] + bias[n]
// 256x256 tile, BK=32, 8 waves (2Mx4N, each owns 128x64 = 8x4 frags).
// 3-deep LDS ring (96KB), COUNTED vmcnt pipeline (T3+T4 essence):
//   iter t: stage tile t+2 -> ring[(t+2)%3]        (4 gloads/thread)
//           s_waitcnt vmcnt(8)   <- waits ONLY tile t; t+1,t+2 stay in flight
//           barrier; ds_read 12 frags + 32 MFMA from ring[t%3]
//           lgkmcnt(0); barrier  <- reads done before slot reuse at t+1
// Race-free: ring slot rewritten exactly 3 tiles after its reads completed
// (ordered by trailing barrier). No vmcnt(0) drain in the main loop.
// ---------------------------------------------------------------------------
__global__ __launch_bounds__(512, 2) void gemm_bt_bias_kernel(
    const bf16_t* __restrict__ xb, const bf16_t* __restrict__ weff,
    const float* __restrict__ bias, float* __restrict__ out) {
  __shared__ __align__(16) bf16_t AsL[3 * 256 * 32];  // 48KB ring
  __shared__ __align__(16) bf16_t BsL[3 * 256 * 32];  // 48KB ring

  int nwg = gridDim.x;   // 1024
  int cpx = nwg >> 3;    // 128
  int bid = blockIdx.x;
  int swz = (bid & 7) * cpx + (bid >> 3);  // bijective XCD swizzle (1024%8==0)
  int mt = swz >> 4;     // 64 m-tiles
  int nt = swz & 15;     // 16 n-tiles
  long blkM = (long)mt << 8;
  long blkN = (long)nt << 8;

  int tid = threadIdx.x;
  int lane = tid & 63;
  int wv = tid >> 6;            // wave 0..7
  int wr = wv >> 2, wc = wv & 3;

  // staging: sweep covers 128 rows (8 waves x 16); lane l -> row l>>2,
  // physical chunk l&3, fetched data chunk = (l&3)^((row>>1)&3)
  int srow = wv * 16 + (lane >> 2);
  int schunk = (lane & 3) ^ ((lane >> 3) & 3);
  const bf16_t* gA = xb + (blkM + srow) * GK + (long)schunk * 8;
  const bf16_t* gB = weff + (blkN + srow) * GK + (long)schunk * 8;
  int ldsOff0 = (wv * 16) * 32;        // sweep 0 (rows 0-127) wave base
  int ldsOff1 = (128 + wv * 16) * 32;  // sweep 1 (rows 128-255)

  // fragment read: row = base + (lane&15), physical chunk =
  // (lane>>4) ^ ((row>>1)&3) = (lane>>4) ^ ((lane>>1)&3)
  int r_l = lane & 15;
  int pcidx = (lane >> 4) ^ ((lane >> 1) & 3);

  f32x4 acc[8][4];
#pragma unroll
  for (int i = 0; i < 8; ++i)
#pragma unroll
    for (int j = 0; j < 4; ++j) acc[i][j] = (f32x4){0.f, 0.f, 0.f, 0.f};

#define STAGE(slot, kt)                                                        \
  {                                                                            \
    long ko = (long)(kt) * 32;                                                 \
    bf16_t* la = AsL + (slot) * 8192;                                          \
    bf16_t* lb = BsL + (slot) * 8192;                                          \
    GLOAD16(gA + ko, la + ldsOff0);                                            \
    GLOAD16(gA + ko + 128L * GK, la + ldsOff1);                                \
    GLOAD16(gB + ko, lb + ldsOff0);                                            \
    GLOAD16(gB + ko + 128L * GK, lb + ldsOff1);                                \
  }

  // prologue: tiles 0 and 1 in flight
  STAGE(0, 0);
  STAGE(1, 1);

  const int NTT = GK / 32;  // 128
  int cur = 0;
  for (int t = 0; t < NTT; ++t) {
    int s2 = cur - 1; if (s2 < 0) s2 = 2;  // (cur+2)%3
    if (t + 2 < NTT) STAGE(s2, t + 2);

    // counted wait: tile t complete; tiles t+1,t+2 (8 loads) stay in flight
    if (t + 2 < NTT) {
      asm volatile("s_waitcnt vmcnt(8)" ::: "memory");
    } else if (t + 1 < NTT) {
      asm volatile("s_waitcnt vmcnt(4)" ::: "memory");
    } else {
      asm volatile("s_waitcnt vmcnt(0)" ::: "memory");
    }
    __builtin_amdgcn_sched_barrier(0);
    __builtin_amdgcn_s_barrier();   // all waves' tile-t stages complete
    __builtin_amdgcn_sched_barrier(0);

    const bf16x8* AsV = (const bf16x8*)(AsL + cur * 8192);
    const bf16x8* BsV = (const bf16x8*)(BsL + cur * 8192);
    bf16x8 af[8], bfr[4];
#pragma unroll
    for (int mi = 0; mi < 8; ++mi)
      af[mi] = AsV[(wr * 128 + mi * 16 + r_l) * 4 + pcidx];
#pragma unroll
    for (int ni = 0; ni < 4; ++ni)
      bfr[ni] = BsV[(wc * 64 + ni * 16 + r_l) * 4 + pcidx];

#pragma unroll
    for (int mi = 0; mi < 8; ++mi)
#pragma unroll
      for (int ni = 0; ni < 4; ++ni)
        acc[mi][ni] = __builtin_amdgcn_mfma_f32_16x16x32_bf16(
            af[mi], bfr[ni], acc[mi][ni], 0, 0, 0);

    asm volatile("s_waitcnt lgkmcnt(0)" ::: "memory");
    __builtin_amdgcn_sched_barrier(0);
    __builtin_amdgcn_s_barrier();   // reads done -> slot reusable next iter
    cur = (cur + 1 == 3) ? 0 : cur + 1;
  }
#undef STAGE

  // epilogue: C/D layout col=lane&15, row=(lane>>4)*4+reg  (+bias)
  long n0 = blkN + wc * 64 + (lane & 15);
  long m0 = blkM + wr * 128 + ((lane >> 4) << 2);
#pragma unroll
  for (int ni = 0; ni < 4; ++ni) {
    float bv = bias[n0 + ni * 16];
#pragma unroll
    for (int mi = 0; mi < 8; ++mi) {
#pragma unroll
      for (int r = 0; r < 4; ++r) {
        out[(m0 + mi * 16 + r) * GN + (n0 + ni * 16)] = acc[mi][ni][r] + bv;
      }
    }
  }
}

// ---------------------------------------------------------------------------
extern "C" void kernel_launch(void* const* d_in, const int* in_sizes, int n_in,
                              void* d_out, int out_size, void* d_ws,
                              size_t ws_size, hipStream_t stream) {
  const float* x = (const float*)d_in[0];      // [4,4096,4096]
  const float* W = (const float*)d_in[1];      // [4096,4096]
  const float* b = (const float*)d_in[2];      // [4096]
  const float* A = (const float*)d_in[3];      // [16,16,4096]
  const float* Bw = (const float*)d_in[4];     // [16,4096,16]
  const float* probs = (const float*)d_in[5];  // [16]
  float* out = (float*)d_out;

  size_t need = (size_t)GM * GK * 2 + (size_t)GN * GK * 2 + 256ull * GN * 4;
  if (ws_size < need) return;  // fail validation cleanly, never write OOB

  bf16_t* xb = (bf16_t*)d_ws;                    // 128 MiB
  bf16_t* weff = xb + (size_t)GM * GK;           // 32 MiB
  float* bpt = (float*)(weff + (size_t)GN * GK); // 4 MiB

  cvt_x_kernel<<<16384, 256, 0, stream>>>(x, xb);
  make_bpt_kernel<<<256, 256, 0, stream>>>(Bw, probs, bpt);
  weff_kernel<<<4096, 256, 0, stream>>>(W, A, bpt, weff);
  gemm_bt_bias_kernel<<<1024, 512, 0, stream>>>(xb, weff, b, out);
}

// Round 6
// 1251.990 us; speedup vs baseline: 1.0225x; 1.0225x over previous
//
#include <hip/hip_runtime.h>
#include <hip/hip_bf16.h>

typedef __bf16 bf16_t;
typedef __attribute__((ext_vector_type(8))) __bf16 bf16x8;
typedef __attribute__((ext_vector_type(4))) __bf16 bf16x4;
typedef __attribute__((ext_vector_type(4))) float f32x4;

#define GM 16384
#define GN 4096
#define GK 4096

// async global->LDS, 16B per lane; LDS dest is wave-uniform base + lane*16
#define GLOAD16(gp, lp)                                                        \
  __builtin_amdgcn_global_load_lds(                                            \
      (const __attribute__((address_space(1))) unsigned int*)(gp),             \
      (__attribute__((address_space(3))) unsigned int*)(lp), 16, 0, 0)

// ---------------------------------------------------------------------------
// Kernel 1: convert x (fp32) -> bf16. Grid-stride (G11): 2048 blocks,
// 16 iterations/thread, 32B read + 16B write per iter.
// ---------------------------------------------------------------------------
__global__ __launch_bounds__(256) void cvt_x_kernel(
    const float* __restrict__ in, bf16_t* __restrict__ outb) {
  const long total = (long)GM * GK / 8;  // bf16x8 chunks
  long stride = (long)gridDim.x * blockDim.x;
  const f32x4* v = (const f32x4*)in;
  bf16x8* o = (bf16x8*)outb;
  for (long i = (long)blockIdx.x * blockDim.x + threadIdx.x; i < total;
       i += stride) {
    f32x4 a = v[2 * i];
    f32x4 b = v[2 * i + 1];
    bf16x8 r;
    r[0] = (__bf16)a[0]; r[1] = (__bf16)a[1]; r[2] = (__bf16)a[2]; r[3] = (__bf16)a[3];
    r[4] = (__bf16)b[0]; r[5] = (__bf16)b[1]; r[6] = (__bf16)b[2]; r[7] = (__bf16)b[3];
    o[i] = r;
  }
}

// ---------------------------------------------------------------------------
// Kernel 2: bpt[er][o] = probs[e] * B[e][o][r]   (round-2 version, 37us)
// ---------------------------------------------------------------------------
__global__ __launch_bounds__(256) void make_bpt_kernel(
    const float* __restrict__ Bw, const float* __restrict__ probs,
    float* __restrict__ bpt) {
  int idx = blockIdx.x * 256 + threadIdx.x;  // 1,048,576 total
  int er = idx >> 12;
  int o = idx & 4095;
  int e = er >> 4, r = er & 15;
  bpt[idx] = probs[e] * Bw[(e << 16) + (o << 4) + r];
}

// ---------------------------------------------------------------------------
// Kernel 3: weff[o][d] = bf16( W[o][d] + sum_er bpt[er][o] * A[er][d] )
// (round-2 version, measured 82us)
// ---------------------------------------------------------------------------
__global__ __launch_bounds__(256) void weff_kernel(
    const float* __restrict__ W, const float* __restrict__ Aw,
    const float* __restrict__ bpt, bf16_t* __restrict__ weffp) {
  __shared__ __align__(16) float At[64 * 64];  // [er][d] 16KB
  __shared__ __align__(16) float Bt[64 * 64];  // [er][o] 16KB
  int tid = threadIdx.x;
  int d0 = (blockIdx.x & 63) << 6;
  int o0 = (blockIdx.x >> 6) << 6;
  int tx = tid & 15, ty = tid >> 4;

  float acc[4][4] = {};

  for (int kc = 0; kc < 256; kc += 64) {
    __syncthreads();
#pragma unroll
    for (int q = 0; q < 4; ++q) {
      int er_l = (tid >> 4) + q * 16;
      f32x4 va = *(const f32x4*)&Aw[(long)(kc + er_l) * 4096 + d0 + tx * 4];
      *(f32x4*)&At[er_l * 64 + tx * 4] = va;
      f32x4 vb = *(const f32x4*)&bpt[(long)(kc + er_l) * 4096 + o0 + tx * 4];
      *(f32x4*)&Bt[er_l * 64 + tx * 4] = vb;
    }
    __syncthreads();
#pragma unroll 8
    for (int kk = 0; kk < 64; ++kk) {
      f32x4 av = *(const f32x4*)&At[kk * 64 + tx * 4];
      f32x4 bv = *(const f32x4*)&Bt[kk * 64 + ty * 4];
#pragma unroll
      for (int i = 0; i < 4; ++i)
#pragma unroll
        for (int j = 0; j < 4; ++j) acc[i][j] = fmaf(bv[i], av[j], acc[i][j]);
    }
  }

#pragma unroll
  for (int i = 0; i < 4; ++i) {
    int o = o0 + ty * 4 + i;
    f32x4 w = *(const f32x4*)&W[(long)o * 4096 + d0 + tx * 4];
    bf16x4 ov;
#pragma unroll
    for (int j = 0; j < 4; ++j) ov[j] = (__bf16)(w[j] + acc[i][j]);
    *(bf16x4*)&weffp[(long)o * 4096 + d0 + tx * 4] = ov;
  }
}

// ---------------------------------------------------------------------------
// Kernel 4: out[m][n] = sum_k xb[m][k]*weff[n][k] + bias[n]
// ROUND-2 VERBATIM (measured 568us, MfmaUtil 46.5%, occupancy 87%):
// m97 structure: 128x128 tile, BK=32, 4 waves (2x2 of 64x64), 16x16x32 MFMA,
// global_load_lds w16, single buffer, 2 syncthreads/K-step. High occupancy
// (5+ blocks/CU) provides the latency fill (m114) — do not trade it away.
// ---------------------------------------------------------------------------
__global__ __launch_bounds__(256) void gemm_bt_bias_kernel(
    const bf16_t* __restrict__ xb, const bf16_t* __restrict__ weff,
    const float* __restrict__ bias, float* __restrict__ out) {
  __shared__ __align__(16) bf16_t As[128 * 32];  // 8KB, [row][k] chunk-swizzled
  __shared__ __align__(16) bf16_t Bs[128 * 32];  // 8KB

  int nwg = gridDim.x;          // 4096
  int cpx = nwg >> 3;           // 512
  int bid = blockIdx.x;
  int swz = (bid & 7) * cpx + (bid >> 3);  // bijective XCD swizzle (4096%8==0)
  int mt = swz >> 5;            // 128 m-tiles
  int nt = swz & 31;            // 32 n-tiles
  int blkM = mt << 7;
  int blkN = nt << 7;

  int tid = threadIdx.x;
  int lane = tid & 63;
  int wv = tid >> 6;            // wave 0..3
  int wr = wv >> 1, wc = wv & 1;

  // staging: wave wv covers rows [wv*32, wv*32+32) via 2 insts of 16 rows.
  // lane l -> row (l>>2), physical chunk (l&3); data chunk = (l&3)^((l>>3)&3)
  int srow = wv * 32 + (lane >> 2);
  int schunk = (lane & 3) ^ ((lane >> 3) & 3);
  const bf16_t* gA = xb + (long)(blkM + srow) * GK + schunk * 8;
  const bf16_t* gB = weff + (long)(blkN + srow) * GK + schunk * 8;
  bf16_t* ldsA0 = &As[(wv * 32) * 32];
  bf16_t* ldsA1 = &As[(wv * 32 + 16) * 32];
  bf16_t* ldsB0 = &Bs[(wv * 32) * 32];
  bf16_t* ldsB1 = &Bs[(wv * 32 + 16) * 32];

  // fragment read: row r = base + (lane&15), logical chunk c = lane>>4,
  // physical chunk = c ^ ((r>>1)&3) = (lane>>4) ^ ((lane>>1)&3)
  int r_l = lane & 15;
  int pcidx = (lane >> 4) ^ ((lane >> 1) & 3);
  const bf16x8* AsV = (const bf16x8*)As;
  const bf16x8* BsV = (const bf16x8*)Bs;

  f32x4 acc[4][4];
#pragma unroll
  for (int i = 0; i < 4; ++i)
#pragma unroll
    for (int j = 0; j < 4; ++j) acc[i][j] = (f32x4){0.f, 0.f, 0.f, 0.f};

  for (int k0 = 0; k0 < GK; k0 += 32) {
    GLOAD16(gA + k0, ldsA0);
    GLOAD16(gA + k0 + 16 * GK, ldsA1);
    GLOAD16(gB + k0, ldsB0);
    GLOAD16(gB + k0 + 16 * GK, ldsB1);
    __syncthreads();  // drains vmcnt -> tiles ready

    bf16x8 af[4], bfr[4];
#pragma unroll
    for (int mi = 0; mi < 4; ++mi)
      af[mi] = AsV[(wr * 64 + mi * 16 + r_l) * 4 + pcidx];
#pragma unroll
    for (int ni = 0; ni < 4; ++ni)
      bfr[ni] = BsV[(wc * 64 + ni * 16 + r_l) * 4 + pcidx];

#pragma unroll
    for (int mi = 0; mi < 4; ++mi)
#pragma unroll
      for (int ni = 0; ni < 4; ++ni)
        acc[mi][ni] = __builtin_amdgcn_mfma_f32_16x16x32_bf16(
            af[mi], bfr[ni], acc[mi][ni], 0, 0, 0);

    __syncthreads();  // reads done before next stage overwrites
  }

  // epilogue: C/D layout col=lane&15, row=(lane>>4)*4+reg  (+bias)
  int n0 = blkN + wc * 64 + (lane & 15);
  int m0 = blkM + wr * 64 + ((lane >> 4) << 2);
#pragma unroll
  for (int ni = 0; ni < 4; ++ni) {
    float bv = bias[n0 + ni * 16];
#pragma unroll
    for (int mi = 0; mi < 4; ++mi) {
#pragma unroll
      for (int r = 0; r < 4; ++r) {
        out[(long)(m0 + mi * 16 + r) * GN + (n0 + ni * 16)] =
            acc[mi][ni][r] + bv;
      }
    }
  }
}

// ---------------------------------------------------------------------------
extern "C" void kernel_launch(void* const* d_in, const int* in_sizes, int n_in,
                              void* d_out, int out_size, void* d_ws,
                              size_t ws_size, hipStream_t stream) {
  const float* x = (const float*)d_in[0];      // [4,4096,4096]
  const float* W = (const float*)d_in[1];      // [4096,4096]
  const float* b = (const float*)d_in[2];      // [4096]
  const float* A = (const float*)d_in[3];      // [16,16,4096]
  const float* Bw = (const float*)d_in[4];     // [16,4096,16]
  const float* probs = (const float*)d_in[5];  // [16]
  float* out = (float*)d_out;

  // workspace layout:
  //   xb   : GM*GK bf16  = 128 MiB
  //   weff : GN*GK bf16  =  32 MiB
  //   bpt  : 256*GN f32  =   4 MiB
  size_t need = (size_t)GM * GK * 2 + (size_t)GN * GK * 2 + 256ull * GN * 4;
  if (ws_size < need) return;  // fail validation cleanly, never write OOB

  bf16_t* xb = (bf16_t*)d_ws;                    // 128 MiB
  bf16_t* weff = xb + (size_t)GM * GK;           // 32 MiB
  float* bpt = (float*)(weff + (size_t)GN * GK); // 4 MiB

  cvt_x_kernel<<<2048, 256, 0, stream>>>(x, xb);
  make_bpt_kernel<<<4096, 256, 0, stream>>>(Bw, probs, bpt);
  weff_kernel<<<4096, 256, 0, stream>>>(W, A, bpt, weff);
  gemm_bt_bias_kernel<<<4096, 256, 0, stream>>>(xb, weff, b, out);
}